// Round 6
// baseline (807.426 us; speedup 1.0000x reference)
//
#include <hip/hip_runtime.h>
#include <hip/hip_bf16.h>

#define Q_TOT 1024
#define T_TOT 256
#define NPTS  100
#define KD    300
#define EPSV  1e-6f

// ---------------------------------------------------------------------------
// One pass: NU shifted dot-products for FOUR queries.  S[c][x] = tgt_ext[x+c]
// (4 byte-rotated copies -> every read is an aligned b128 with compile-time
// offset, broadcast across lanes -> conflict-free).  A[a,k] = tgt_ext[300-3a+k].
// Each LDS b128 now feeds 16 FMAs (4 queries x float4): the per-CU LDS pipe
// (~12 cyc/b128, shared by 4 SIMDs) was the R5 bottleneck at 8 FMAs/read.
// ---------------------------------------------------------------------------
template<int ABASE, int NU, bool P2>
__device__ __forceinline__ void dot_pass(const float (&S)[4][608],
                                         const float4* __restrict__ pp,
                                         float (&acc)[NU][4], float (&p2)[4])
{
    #pragma unroll
    for (int u = 0; u < NU; ++u)
        #pragma unroll
        for (int j = 0; j < 4; ++j) acc[u][j] = 0.f;
    #pragma clang loop unroll(disable)
    for (int kc = 0; kc < 75; ++kc) {
        float4 p[4];
        #pragma unroll
        for (int j = 0; j < 4; ++j) p[j] = pp[j*4800 + kc];   // queries lane+64j
        if (P2) {
            #pragma unroll
            for (int j = 0; j < 4; ++j)
                p2[j] = fmaf(p[j].x,p[j].x, fmaf(p[j].y,p[j].y,
                         fmaf(p[j].z,p[j].z, fmaf(p[j].w,p[j].w, p2[j]))));
        }
        #pragma unroll
        for (int u = 0; u < NU; ++u) {
            const int a   = ABASE + u;          // shift amount (compile-time)
            const int off = 300 - 3*a;          // base into tgt_ext
            const int c   = off & 3;            // which rotated copy
            const int y   = (off - c) + kc*4;   // 16B-aligned float index
            const float4 a4 = *reinterpret_cast<const float4*>(&S[c][y]);
            #pragma unroll
            for (int j = 0; j < 4; ++j)
                acc[u][j] = fmaf(a4.x,p[j].x, fmaf(a4.y,p[j].y,
                             fmaf(a4.z,p[j].z, fmaf(a4.w,p[j].w, acc[u][j]))));
        }
    }
}

template<int NU>
__device__ __forceinline__ void fold_min4(const float (&acc)[NU][4], const float (&s2)[4],
                                          int vbase, float (&dmin)[4], int (&imin)[4])
{
    #pragma unroll
    for (int u = 0; u < NU; ++u)
        #pragma unroll
        for (int j = 0; j < 4; ++j) {
            float d2 = fmaxf(fmaf(-2.f, acc[u][j], s2[j]), 0.f) * 0.01f;
            if (d2 < dmin[j]) { dmin[j] = d2; imin[j] = vbase + u; } // strict < = first occ.
        }
}

// 25 variants for this wave, split 13+12 so the two passes' accumulator
// registers never coexist (R4's spill lesson).  Fold ascending in v.
template<int ABASE, int VBASE>
__device__ __forceinline__ void process(const float (&S)[4][608],
                                        const float4* __restrict__ pp, float v2,
                                        float (&dmin)[4], int (&imin)[4], float (&df)[4])
{
    float p2[4] = {0.f,0.f,0.f,0.f};
    float s2[4];
    {
        float acc[13][4];
        dot_pass<ABASE, 13, true>(S, pp, acc, p2);
        #pragma unroll
        for (int j = 0; j < 4; ++j) s2[j] = v2 + p2[j];
        if (VBASE == 0 || VBASE == 100) {       // d2 at v=0 (fwd) / v=100 (bwd)
            #pragma unroll
            for (int j = 0; j < 4; ++j)
                df[j] = fmaxf(fmaf(-2.f, acc[0][j], s2[j]), 0.f) * 0.01f;
        }
        fold_min4<13>(acc, s2, VBASE, dmin, imin);
    }
    {
        float acc[12][4];
        dot_pass<ABASE+13, 12, false>(S, pp, acc, p2);
        fold_min4<12>(acc, s2, VBASE+13, dmin, imin);
    }
}

// ---------------------------------------------------------------------------
// One block = one target t x 256 queries.  512 threads = 8 variant-groups
// (waves) x 64 lanes; each thread: 25 variants x 4 queries x 300-MAC dots.
// ---------------------------------------------------------------------------
__global__ __launch_bounds__(512, 2) void matcher_main(
    const float* __restrict__ preds,   // [1024][300]
    const float* __restrict__ plog,    // [1024][2]
    const float* __restrict__ ptyp,    // [1024][4]
    const float* __restrict__ clog,    // [1024][2]
    const float* __restrict__ tgt,     // [256][300]
    const int*   __restrict__ labels,  // [256]
    const int*   __restrict__ iscl,    // [256]
    const float* __restrict__ clw,     // [256]
    float* __restrict__ out)           // [2][1024][256] flat fp32
{
    __shared__ __align__(16) float sF[4][608];   // fwd tgt_ext, 4 rotated copies
    __shared__ __align__(16) float sR[4][608];   // reversed tgt_ext, 4 copies
    __shared__ float red_min[8][256];
    __shared__ int   red_idx[8][256];
    __shared__ float red_open[2][256];

    const int t    = blockIdx.x;
    const int qt   = blockIdx.y;        // 0..3
    const int tid  = threadIdx.x;
    const int lane = tid & 63;
    const int vg   = tid >> 6;          // 0..7, wave-uniform
    const int qa0  = qt*256 + lane;     // first of 4 queries (stride 64)

    // Stage tgt_ext (doubled 300) fwd + reversed, 4 byte-rotated copies.
    const float* tg = tgt + t*KD;
    for (int i = tid; i < 600; i += 512) {
        int m = (i >= 300) ? (i-300) : i;
        float vF = tg[m];
        int jj = m / 3;
        int c3 = m - jj*3;
        float vR = tg[(NPTS-1-jj)*3 + c3];
        #pragma unroll
        for (int c = 0; c < 4; ++c) {
            int x = i - c;
            if (x >= 0) { sF[c][x] = vF; sR[c][x] = vR; }
        }
    }
    __syncthreads();

    // v2 = sum(tgt^2) -- broadcast LDS reads
    float v2 = 0.f;
    {
        const float4* tf4 = reinterpret_cast<const float4*>(&sF[0][300]); // = tg[0..299]
        #pragma clang loop unroll(disable)
        for (int i2 = 0; i2 < 75; ++i2) {
            float4 w = tf4[i2];
            v2 = fmaf(w.x,w.x, fmaf(w.y,w.y, fmaf(w.z,w.z, fmaf(w.w,w.w, v2))));
        }
    }

    const float4* pp = reinterpret_cast<const float4*>(preds) + qa0*75;
    float dmin[4] = {3.4028235e38f,3.4028235e38f,3.4028235e38f,3.4028235e38f};
    int   imin[4] = {0,0,0,0};
    float df[4]   = {0.f,0.f,0.f,0.f};
    switch (vg) {                       // wave-uniform branch
        case 0:  process<0 ,  0>(sF, pp, v2, dmin, imin, df); break;
        case 1:  process<25, 25>(sF, pp, v2, dmin, imin, df); break;
        case 2:  process<50, 50>(sF, pp, v2, dmin, imin, df); break;
        case 3:  process<75, 75>(sF, pp, v2, dmin, imin, df); break;
        case 4:  process<0 ,100>(sR, pp, v2, dmin, imin, df); break;
        case 5:  process<25,125>(sR, pp, v2, dmin, imin, df); break;
        case 6:  process<50,150>(sR, pp, v2, dmin, imin, df); break;
        default: process<75,175>(sR, pp, v2, dmin, imin, df); break;
    }

    #pragma unroll
    for (int j = 0; j < 4; ++j) {
        red_min[vg][lane + 64*j] = dmin[j];
        red_idx[vg][lane + 64*j] = imin[j];
    }
    if (vg == 0) {
        #pragma unroll
        for (int j = 0; j < 4; ++j) red_open[0][lane + 64*j] = df[j];  // d2[v=0]
    }
    if (vg == 4) {
        #pragma unroll
        for (int j = 0; j < 4; ++j) red_open[1][lane + 64*j] = df[j];  // d2[v=100]
    }
    __syncthreads();

    if (tid < 256) {
        float mbest = red_min[0][tid]; int ibest = red_idx[0][tid];
        #pragma unroll
        for (int g = 1; g < 8; ++g) {         // ascending v-groups, strict <
            float mg = red_min[g][tid];
            if (mg < mbest) { mbest = mg; ibest = red_idx[g][tid]; }
        }
        int mapped = (ibest <= NPTS-1) ? ibest : (2*NPTS-1 - ibest);
        float od   = fminf(red_open[0][tid], red_open[1][tid]);
        int   isc  = iscl[t];                 // 0 or 1
        float geom = isc ? mbest : od;
        int   ido  = isc ? mapped : 0;
        geom *= clw[t];

        // Inline cost-class terms for query qg, target t.
        const int qg = qt*256 + tid;
        float t0 = ptyp[qg*4+0], t1 = ptyp[qg*4+1];
        float t2 = ptyp[qg*4+2], t3 = ptyp[qg*4+3];
        float mx = fmaxf(fmaxf(t0,t1), fmaxf(t2,t3));
        float e0 = expf(t0-mx), e1 = expf(t1-mx), e2 = expf(t2-mx), e3 = expf(t3-mx);
        float rs = 1.0f/(e0+e1+e2+e3);
        int lab  = labels[t];
        float el = (lab == 0) ? e0 : (lab == 1) ? e1 : (lab == 2) ? e2 : e3;
        float cost = -logf(el*rs + EPSV);
        float v0 = plog[qg*2+0], v1 = plog[qg*2+1];
        cost += -logf(1.0f/(1.0f + expf(v1-v0)) + EPSV);
        float c0 = clog[qg*2+0], c1 = clog[qg*2+1];
        float pc = isc ? (1.0f/(1.0f + expf(c0-c1))) : (1.0f/(1.0f + expf(c1-c0)));
        cost += -logf(pc + EPSV);

        float C = geom + cost;
        out[qg*T_TOT + t]               = C;
        out[Q_TOT*T_TOT + qg*T_TOT + t] = (float)ido;
    }
}

extern "C" void kernel_launch(void* const* d_in, const int* in_sizes, int n_in,
                              void* d_out, int out_size, void* d_ws, size_t ws_size,
                              hipStream_t stream)
{
    const float* preds  = (const float*)d_in[0];  // pred_curve_points (1,1024,100,3)
    const float* plog   = (const float*)d_in[1];  // pred_curve_logits (1,1024,2)
    const float* ptyp   = (const float*)d_in[2];  // pred_curve_type   (1,1024,4)
    const float* clog   = (const float*)d_in[3];  // closed_curve_logits (1,1024,2)
    const float* tgt    = (const float*)d_in[4];  // tgt_curve_points  (256,100,3)
    const int*   labels = (const int*)d_in[5];    // tgt_labels (256)
    const int*   iscl   = (const int*)d_in[6];    // tgt_is_closed (256)
    const float* clw    = (const float*)d_in[7];  // curve_length_weighting (256)
    float* out = (float*)d_out;

    matcher_main<<<dim3(T_TOT, Q_TOT/256), dim3(512), 0, stream>>>(
        preds, plog, ptyp, clog, tgt, labels, iscl, clw, out);
}

// Round 7
// 463.326 us; speedup vs baseline: 1.7427x; 1.7427x over previous
//
#include <hip/hip_runtime.h>
#include <hip/hip_bf16.h>

#define Q_TOT 1024
#define T_TOT 256
#define NPTS  100
#define KD    300
#define EPSV  1e-6f

// d_ws layout (floats):
//   [0, 256*1216)           : per-target ext buffers: t*1216 + [0,600) fwd_ext,
//                             t*1216 + 608 + [0,600) bwd_ext
//   [WS_PT, WS_PT+75*1024*4): preds transposed: predT[kc][q] as float4
#define WS_PT (T_TOT*1216)

// ---------------------------------------------------------------------------
// Prep A: doubled fwd/bwd target buffers (read by MAIN via uniform s_loads).
// ---------------------------------------------------------------------------
__global__ void prep_tgt_ext(const float* __restrict__ tgt, float* __restrict__ ws)
{
    const int t = blockIdx.x;
    const float* tg = tgt + t*KD;
    float* wF = ws + t*1216;
    float* wR = wF + 608;
    for (int x = threadIdx.x; x < 600; x += blockDim.x) {
        int m = (x >= 300) ? (x-300) : x;
        int jj = m / 3;
        int c3 = m - jj*3;
        wF[x] = tg[m];
        wR[x] = tg[(NPTS-1-jj)*3 + c3];
    }
}

// ---------------------------------------------------------------------------
// Prep B: transpose preds to [kc][q] float4 so main-loop pred loads are
// lane-contiguous (old [q][kc] layout touched 64 cache lines per instr).
// ---------------------------------------------------------------------------
__global__ void prep_predT(const float4* __restrict__ preds4, float4* __restrict__ pT)
{
    int i = blockIdx.x * blockDim.x + threadIdx.x;   // i = kc*1024 + q
    if (i >= 75*Q_TOT) return;
    int kc = i >> 10;
    int q  = i & 1023;
    pT[i] = preds4[q*75 + kc];
}

// ---------------------------------------------------------------------------
// One pass: NU shifted dot-products for FOUR queries.  Target values come from
// wave-uniform scalar loads (s_load / K$) -- zero LDS, zero extra vmem; each
// v_fma uses the free single-SGPR operand slot.  A[a,k] = tgt_ext[300-3a+k].
// ---------------------------------------------------------------------------
template<int ABASE, int NU, bool P2>
__device__ __forceinline__ void dot_pass(const float* __restrict__ tw,    // uniform
                                         const float4* __restrict__ pT,   // +lane offset
                                         float (&acc)[NU][4], float (&p2)[4])
{
    #pragma unroll
    for (int u = 0; u < NU; ++u)
        #pragma unroll
        for (int j = 0; j < 4; ++j) acc[u][j] = 0.f;
    #pragma clang loop unroll(disable)
    for (int kc = 0; kc < 75; ++kc) {
        float4 p[4];
        #pragma unroll
        for (int j = 0; j < 4; ++j) p[j] = pT[kc*1024 + 64*j];
        if (P2) {
            #pragma unroll
            for (int j = 0; j < 4; ++j)
                p2[j] = fmaf(p[j].x,p[j].x, fmaf(p[j].y,p[j].y,
                         fmaf(p[j].z,p[j].z, fmaf(p[j].w,p[j].w, p2[j]))));
        }
        const float* twk = tw + 4*kc;            // uniform, advances 16B/iter
        #pragma unroll
        for (int u = 0; u < NU; ++u) {
            const int off = 300 - 3*(ABASE + u); // compile-time
            float a0 = twk[off+0], a1 = twk[off+1], a2 = twk[off+2], a3 = twk[off+3];
            #pragma unroll
            for (int j = 0; j < 4; ++j)
                acc[u][j] = fmaf(a0,p[j].x, fmaf(a1,p[j].y,
                             fmaf(a2,p[j].z, fmaf(a3,p[j].w, acc[u][j]))));
        }
    }
}

template<int NU>
__device__ __forceinline__ void fold_min4(const float (&acc)[NU][4], const float (&s2)[4],
                                          int vbase, float (&dmin)[4], int (&imin)[4])
{
    #pragma unroll
    for (int u = 0; u < NU; ++u)
        #pragma unroll
        for (int j = 0; j < 4; ++j) {
            float d2 = fmaxf(fmaf(-2.f, acc[u][j], s2[j]), 0.f) * 0.01f;
            if (d2 < dmin[j]) { dmin[j] = d2; imin[j] = vbase + u; } // strict < = first occ.
        }
}

// 25 variants for this wave, split 13+12 (R4's spill lesson: passes' registers
// must not coexist).  Fold ascending in v.
template<int ABASE, int VBASE>
__device__ __forceinline__ void process(const float* __restrict__ tw,
                                        const float4* __restrict__ pT, float v2,
                                        float (&dmin)[4], int (&imin)[4], float (&df)[4])
{
    float p2[4] = {0.f,0.f,0.f,0.f};
    float s2[4];
    {
        float acc[13][4];
        dot_pass<ABASE, 13, true>(tw, pT, acc, p2);
        #pragma unroll
        for (int j = 0; j < 4; ++j) s2[j] = v2 + p2[j];
        if (VBASE == 0 || VBASE == 100) {       // d2 at v=0 (fwd) / v=100 (bwd)
            #pragma unroll
            for (int j = 0; j < 4; ++j)
                df[j] = fmaxf(fmaf(-2.f, acc[0][j], s2[j]), 0.f) * 0.01f;
        }
        fold_min4<13>(acc, s2, VBASE, dmin, imin);
    }
    {
        float acc[12][4];
        dot_pass<ABASE+13, 12, false>(tw, pT, acc, p2);
        fold_min4<12>(acc, s2, VBASE+13, dmin, imin);
    }
}

// ---------------------------------------------------------------------------
// One block = one target t x 256 queries.  512 threads = 8 variant-groups
// (waves) x 64 lanes; each thread: 25 variants x 4 queries x 300-MAC dots.
// ---------------------------------------------------------------------------
__global__ __launch_bounds__(512, 2) void matcher_main(
    const float* __restrict__ ws,      // prep output (tgt ext + predT)
    const float* __restrict__ plog,    // [1024][2]
    const float* __restrict__ ptyp,    // [1024][4]
    const float* __restrict__ clog,    // [1024][2]
    const int*   __restrict__ labels,  // [256]
    const int*   __restrict__ iscl,    // [256]
    const float* __restrict__ clw,     // [256]
    float* __restrict__ out)           // [2][1024][256] flat fp32
{
    __shared__ float red_min[8][256];
    __shared__ int   red_idx[8][256];
    __shared__ float red_open[2][256];

    const int t    = blockIdx.x;
    const int qt   = blockIdx.y;        // 0..3
    const int tid  = threadIdx.x;
    const int lane = tid & 63;
    const int vg   = tid >> 6;          // 0..7, uniform per wave

    const float* twF = ws + t*1216;     // uniform bases -> scalar loads
    const float* twR = twF + 608;
    const float4* pT = reinterpret_cast<const float4*>(ws + WS_PT) + (qt*256 + lane);

    // v2 = sum(tgt^2), same fmaf chain/order as before (bit-identical results)
    float v2 = 0.f;
    #pragma clang loop unroll(disable)
    for (int i = 0; i < 75; ++i) {
        float a0 = twF[300+4*i+0], a1 = twF[300+4*i+1];
        float a2 = twF[300+4*i+2], a3 = twF[300+4*i+3];
        v2 = fmaf(a0,a0, fmaf(a1,a1, fmaf(a2,a2, fmaf(a3,a3, v2))));
    }

    float dmin[4] = {3.4028235e38f,3.4028235e38f,3.4028235e38f,3.4028235e38f};
    int   imin[4] = {0,0,0,0};
    float df[4]   = {0.f,0.f,0.f,0.f};
    const int svg = __builtin_amdgcn_readfirstlane(vg);   // provably uniform
    switch (svg) {
        case 0:  process<0 ,  0>(twF, pT, v2, dmin, imin, df); break;
        case 1:  process<25, 25>(twF, pT, v2, dmin, imin, df); break;
        case 2:  process<50, 50>(twF, pT, v2, dmin, imin, df); break;
        case 3:  process<75, 75>(twF, pT, v2, dmin, imin, df); break;
        case 4:  process<0 ,100>(twR, pT, v2, dmin, imin, df); break;
        case 5:  process<25,125>(twR, pT, v2, dmin, imin, df); break;
        case 6:  process<50,150>(twR, pT, v2, dmin, imin, df); break;
        default: process<75,175>(twR, pT, v2, dmin, imin, df); break;
    }

    #pragma unroll
    for (int j = 0; j < 4; ++j) {
        red_min[vg][lane + 64*j] = dmin[j];
        red_idx[vg][lane + 64*j] = imin[j];
    }
    if (vg == 0) {
        #pragma unroll
        for (int j = 0; j < 4; ++j) red_open[0][lane + 64*j] = df[j];  // d2[v=0]
    }
    if (vg == 4) {
        #pragma unroll
        for (int j = 0; j < 4; ++j) red_open[1][lane + 64*j] = df[j];  // d2[v=100]
    }
    __syncthreads();

    if (tid < 256) {
        float mbest = red_min[0][tid]; int ibest = red_idx[0][tid];
        #pragma unroll
        for (int g = 1; g < 8; ++g) {         // ascending v-groups, strict <
            float mg = red_min[g][tid];
            if (mg < mbest) { mbest = mg; ibest = red_idx[g][tid]; }
        }
        int mapped = (ibest <= NPTS-1) ? ibest : (2*NPTS-1 - ibest);
        float od   = fminf(red_open[0][tid], red_open[1][tid]);
        int   isc  = iscl[t];                 // 0 or 1
        float geom = isc ? mbest : od;
        int   ido  = isc ? mapped : 0;
        geom *= clw[t];

        // Inline cost-class terms for query qg, target t.
        const int qg = qt*256 + tid;
        float t0 = ptyp[qg*4+0], t1 = ptyp[qg*4+1];
        float t2 = ptyp[qg*4+2], t3 = ptyp[qg*4+3];
        float mx = fmaxf(fmaxf(t0,t1), fmaxf(t2,t3));
        float e0 = expf(t0-mx), e1 = expf(t1-mx), e2 = expf(t2-mx), e3 = expf(t3-mx);
        float rs = 1.0f/(e0+e1+e2+e3);
        int lab  = labels[t];
        float el = (lab == 0) ? e0 : (lab == 1) ? e1 : (lab == 2) ? e2 : e3;
        float cost = -logf(el*rs + EPSV);
        float v0 = plog[qg*2+0], v1 = plog[qg*2+1];
        cost += -logf(1.0f/(1.0f + expf(v1-v0)) + EPSV);
        float c0 = clog[qg*2+0], c1 = clog[qg*2+1];
        float pc = isc ? (1.0f/(1.0f + expf(c0-c1))) : (1.0f/(1.0f + expf(c1-c0)));
        cost += -logf(pc + EPSV);

        float C = geom + cost;
        out[qg*T_TOT + t]               = C;
        out[Q_TOT*T_TOT + qg*T_TOT + t] = (float)ido;
    }
}

extern "C" void kernel_launch(void* const* d_in, const int* in_sizes, int n_in,
                              void* d_out, int out_size, void* d_ws, size_t ws_size,
                              hipStream_t stream)
{
    const float* preds  = (const float*)d_in[0];  // pred_curve_points (1,1024,100,3)
    const float* plog   = (const float*)d_in[1];  // pred_curve_logits (1,1024,2)
    const float* ptyp   = (const float*)d_in[2];  // pred_curve_type   (1,1024,4)
    const float* clog   = (const float*)d_in[3];  // closed_curve_logits (1,1024,2)
    const float* tgt    = (const float*)d_in[4];  // tgt_curve_points  (256,100,3)
    const int*   labels = (const int*)d_in[5];    // tgt_labels (256)
    const int*   iscl   = (const int*)d_in[6];    // tgt_is_closed (256)
    const float* clw    = (const float*)d_in[7];  // curve_length_weighting (256)
    float* out = (float*)d_out;
    float* ws  = (float*)d_ws;    // needs (256*1216 + 75*1024*4)*4 B = 2.47 MB

    prep_tgt_ext<<<dim3(T_TOT), dim3(256), 0, stream>>>(tgt, ws);
    prep_predT<<<dim3((75*Q_TOT + 255)/256), dim3(256), 0, stream>>>(
        (const float4*)preds, (float4*)(ws + WS_PT));
    matcher_main<<<dim3(T_TOT, Q_TOT/256), dim3(512), 0, stream>>>(
        ws, plog, ptyp, clog, labels, iscl, clw, out);
}